// Round 15
// baseline (575.180 us; speedup 1.0000x reference)
//
#include <hip/hip_runtime.h>
#include <hip/hip_bf16.h>

typedef __attribute__((ext_vector_type(8))) short s16x8;
typedef __attribute__((ext_vector_type(4))) float f32x4;
typedef unsigned short u16;
typedef unsigned int u32;

__device__ __forceinline__ u16 f2b(float f) {
    u32 u = __float_as_uint(f);
    u32 r = (u + 0x7fffu + ((u >> 16) & 1u)) >> 16;  // RNE bf16
    return (u16)r;
}
__device__ __forceinline__ float b2f(u16 b) {
    return __uint_as_float(((u32)b) << 16);
}

#define MFMA16(a, b, c) __builtin_amdgcn_mfma_f32_16x16x32_bf16(a, b, c, 0, 0, 0)
#define GLDS(gp, lp)                                                              \
    __builtin_amdgcn_global_load_lds((const __attribute__((address_space(1))) void*)(gp), \
                                     (__attribute__((address_space(3))) void*)(lp), 16, 0, 0)

// ---------------- elementwise: f32 -> bf16 ----------------
__global__ void k_f2b(const float* __restrict__ in, u16* __restrict__ out, int n4) {
    int i = blockIdx.x * 256 + threadIdx.x;
    if (i >= n4) return;
    float4 v = ((const float4*)in)[i];
    ushort4 o;
    o.x = f2b(v.x); o.y = f2b(v.y); o.z = f2b(v.z); o.w = f2b(v.w);
    ((ushort4*)out)[i] = o;
}

// ---------------- weight transpose+convert: W[K,N] f32 -> Wt[N,K] bf16 ----------------
__global__ void k_wtrans(const float* __restrict__ W, u16* __restrict__ Wt, int K, int N) {
    __shared__ float t[32][33];
    int bx = blockIdx.x * 32, by = blockIdx.y * 32;
    int tx = threadIdx.x, ty = threadIdx.y;
    for (int i = 0; i < 32; i += 8)
        t[ty + i][tx] = W[(size_t)(by + ty + i) * N + bx + tx];
    __syncthreads();
    for (int i = 0; i < 32; i += 8)
        Wt[(size_t)(bx + ty + i) * K + by + tx] = f2b(t[tx][ty + i]);
}

// ---------------- fused QKV GEMM: epilogue writes Qb/Kb (bias only) + transposed Vt ----------------
__global__ __launch_bounds__(256) void gemm_qkv(const u16* __restrict__ A, const u16* __restrict__ Bt,
                                                const float* __restrict__ bq, const float* __restrict__ bk,
                                                const float* __restrict__ bv,
                                                u16* __restrict__ Qb, u16* __restrict__ Kb,
                                                u16* __restrict__ Vt) {
    __shared__ __align__(16) short lA[128 * 64];
    __shared__ __align__(16) short lB[128 * 64];
    const int tid = threadIdx.x, lane = tid & 63, w = tid >> 6;
    const int l15 = lane & 15, lg = lane >> 4;
    const int wr = w >> 1, wc = w & 1;
    const int m0 = blockIdx.y * 128, n0 = blockIdx.x * 128;
    const int KK = 1024;
    f32x4 acc[4][4] = {};

    for (int k0 = 0; k0 < KK; k0 += 64) {
        #pragma unroll
        for (int i = 0; i < 4; i++) {
            int chunk = w * 4 + i;
            int arow = m0 + chunk * 8 + (lane >> 3);
            GLDS(A + (size_t)arow * KK + k0 + (lane & 7) * 8, (short*)lA + chunk * 512);
            int brow = n0 + chunk * 8 + (lane >> 3);
            GLDS(Bt + (size_t)brow * KK + k0 + (lane & 7) * 8, (short*)lB + chunk * 512);
        }
        __syncthreads();
        #pragma unroll
        for (int ks = 0; ks < 2; ks++) {
            s16x8 af[4], bfr[4];
            #pragma unroll
            for (int m = 0; m < 4; m++)
                af[m] = *(const s16x8*)&lA[(wr * 64 + m * 16 + l15) * 64 + ks * 32 + lg * 8];
            #pragma unroll
            for (int n = 0; n < 4; n++)
                bfr[n] = *(const s16x8*)&lB[(wc * 64 + n * 16 + l15) * 64 + ks * 32 + lg * 8];
            #pragma unroll
            for (int m = 0; m < 4; m++)
                #pragma unroll
                for (int n = 0; n < 4; n++)
                    acc[m][n] = MFMA16(af[m], bfr[n], acc[m][n]);
        }
        __syncthreads();
    }
    const int rbase = m0 + wr * 64, cbase = n0 + wc * 64;
    const int seg = cbase >> 10;
    #pragma unroll
    for (int m = 0; m < 4; m++)
        #pragma unroll
        for (int n = 0; n < 4; n++) {
            int col = cbase + n * 16 + l15;
            int c1 = col & 1023, d = col & 63;
            int row0 = rbase + m * 16 + lg * 4;
            if (seg == 0) {
                float bb = bq[c1];
                #pragma unroll
                for (int r = 0; r < 4; r++)
                    Qb[(size_t)(row0 + r) * 1024 + c1] = f2b(acc[m][n][r] + bb);
            } else if (seg == 1) {
                float bb = bk[c1];
                #pragma unroll
                for (int r = 0; r < 4; r++)
                    Kb[(size_t)(row0 + r) * 1024 + c1] = f2b(acc[m][n][r] + bb);
            } else {
                float bb = bv[c1];
                #pragma unroll
                for (int r = 0; r < 4; r++) {
                    int row = row0 + r;
                    size_t o = (size_t)(row >> 6) * 65536 + (size_t)d * 1024 + (row & 63) * 16 + (c1 >> 6);
                    Vt[o] = f2b(acc[m][n][r] + bb);
                }
            }
        }
}

// ---------------- GEMM 128x128, EPI 1: bf16(relu(acc+bias)) ----------------
template <int EPI>
__global__ __launch_bounds__(256) void gemm_bt(const u16* __restrict__ A, const u16* __restrict__ Bt,
                                               void* __restrict__ Cv, int M, int N, int K,
                                               const float* __restrict__ bias) {
    __shared__ __align__(16) short lA[128 * 64];
    __shared__ __align__(16) short lB[128 * 64];
    const int tid = threadIdx.x, lane = tid & 63, w = tid >> 6;
    const int l15 = lane & 15, lg = lane >> 4;
    const int wr = w >> 1, wc = w & 1;
    const int m0 = blockIdx.y * 128, n0 = blockIdx.x * 128;
    f32x4 acc[4][4] = {};

    for (int k0 = 0; k0 < K; k0 += 64) {
        #pragma unroll
        for (int i = 0; i < 4; i++) {
            int chunk = w * 4 + i;
            int arow = m0 + chunk * 8 + (lane >> 3);
            GLDS(A + (size_t)arow * K + k0 + (lane & 7) * 8, (short*)lA + chunk * 512);
            int brow = n0 + chunk * 8 + (lane >> 3);
            GLDS(Bt + (size_t)brow * K + k0 + (lane & 7) * 8, (short*)lB + chunk * 512);
        }
        __syncthreads();
        #pragma unroll
        for (int ks = 0; ks < 2; ks++) {
            s16x8 af[4], bfr[4];
            #pragma unroll
            for (int m = 0; m < 4; m++)
                af[m] = *(const s16x8*)&lA[(wr * 64 + m * 16 + l15) * 64 + ks * 32 + lg * 8];
            #pragma unroll
            for (int n = 0; n < 4; n++)
                bfr[n] = *(const s16x8*)&lB[(wc * 64 + n * 16 + l15) * 64 + ks * 32 + lg * 8];
            #pragma unroll
            for (int m = 0; m < 4; m++)
                #pragma unroll
                for (int n = 0; n < 4; n++)
                    acc[m][n] = MFMA16(af[m], bfr[n], acc[m][n]);
        }
        __syncthreads();
    }
    const int rbase = m0 + wr * 64, cbase = n0 + wc * 64;
    #pragma unroll
    for (int m = 0; m < 4; m++)
        #pragma unroll
        for (int n = 0; n < 4; n++) {
            int col = cbase + n * 16 + l15;
            int row0 = rbase + m * 16 + lg * 4;
            u16* C = (u16*)Cv;
            float bv = bias[col];
            #pragma unroll
            for (int r = 0; r < 4; r++)
                C[(size_t)(row0 + r) * N + col] = f2b(fmaxf(acc[m][n][r] + bv, 0.f));
        }
}

// ---------------- GEMM 128x64 f32-out ----------------
__global__ __launch_bounds__(256) void gemm_bt64(const u16* __restrict__ A, const u16* __restrict__ Bt,
                                                 float* __restrict__ C, int M, int N, int K) {
    __shared__ __align__(16) short lA[128 * 64];
    __shared__ __align__(16) short lB[64 * 64];
    const int tid = threadIdx.x, lane = tid & 63, w = tid >> 6;
    const int l15 = lane & 15, lg = lane >> 4;
    const int m0 = blockIdx.y * 128, n0 = blockIdx.x * 64;
    f32x4 acc[2][4] = {};

    for (int k0 = 0; k0 < K; k0 += 64) {
        #pragma unroll
        for (int i = 0; i < 4; i++) {
            int chunk = w * 4 + i;
            int arow = m0 + chunk * 8 + (lane >> 3);
            GLDS(A + (size_t)arow * K + k0 + (lane & 7) * 8, (short*)lA + chunk * 512);
        }
        #pragma unroll
        for (int i = 0; i < 2; i++) {
            int chunk = w * 2 + i;
            int brow = n0 + chunk * 8 + (lane >> 3);
            GLDS(Bt + (size_t)brow * K + k0 + (lane & 7) * 8, (short*)lB + chunk * 512);
        }
        __syncthreads();
        #pragma unroll
        for (int ks = 0; ks < 2; ks++) {
            s16x8 af[2], bfr[4];
            #pragma unroll
            for (int m = 0; m < 2; m++)
                af[m] = *(const s16x8*)&lA[(w * 32 + m * 16 + l15) * 64 + ks * 32 + lg * 8];
            #pragma unroll
            for (int n = 0; n < 4; n++)
                bfr[n] = *(const s16x8*)&lB[(n * 16 + l15) * 64 + ks * 32 + lg * 8];
            #pragma unroll
            for (int m = 0; m < 2; m++)
                #pragma unroll
                for (int n = 0; n < 4; n++)
                    acc[m][n] = MFMA16(af[m], bfr[n], acc[m][n]);
        }
        __syncthreads();
    }
    #pragma unroll
    for (int m = 0; m < 2; m++)
        #pragma unroll
        for (int n = 0; n < 4; n++) {
            int col = n0 + n * 16 + l15;
            int row0 = m0 + w * 32 + m * 16 + lg * 4;
            #pragma unroll
            for (int r = 0; r < 4; r++)
                C[(size_t)(row0 + r) * N + col] = acc[m][n][r];
        }
}

// ---------------- fa/fc: per-k rel factors fa[g,k]=exp(ra.K[g,k]/8) ----------------
__global__ void k_fvec(const u16* __restrict__ Kb, const float* __restrict__ rel,
                       float* __restrict__ fa, float* __restrict__ fc) {
    __shared__ float rs[128];
    const int g = blockIdx.x, tid = threadIdx.x;
    if (tid < 128) rs[tid] = rel[tid];
    __syncthreads();
    for (int k = tid; k < 1024; k += 256) {
        const u16* kr = Kb + (size_t)g * 65536 + (size_t)k * 64;
        float sa = 0.f, sc = 0.f;
        #pragma unroll
        for (int j = 0; j < 8; j++) {
            s16x8 v = *(const s16x8*)(kr + j * 8);
            #pragma unroll
            for (int e = 0; e < 8; e++) {
                float kv = b2f((u16)v[e]);
                sa += kv * rs[j * 8 + e];
                sc += kv * rs[64 + j * 8 + e];
            }
        }
        fa[g * 1024 + k] = __expf(sa * 0.125f);
        fc[g * 1024 + k] = __expf(sc * 0.125f);
    }
}

// ---------------- E0 = exp(QK^T/8) bf16 row-major + denominators la,lc ----------------
__global__ __launch_bounds__(256, 2) void k_qke0(const u16* __restrict__ Qb, const u16* __restrict__ Kb,
                                                 const float* __restrict__ fa, const float* __restrict__ fc,
                                                 u16* __restrict__ E0,
                                                 float* __restrict__ la_, float* __restrict__ lc_) {
    const int bid = blockIdx.x;
    const int xcd = bid & 7, j = bid >> 3;
    const int g = xcd * 8 + (j & 7), qt = j >> 3;
    const int tid = threadIdx.x, lane = tid & 63, w = tid >> 6;
    const int l15 = lane & 15, lg = lane >> 4;
    __shared__ __align__(16) float lE[4][16][68];

    const int q0 = qt * 64 + w * 16;
    const size_t gQ = (size_t)g * 65536;
    const float scale = 0.125f;

    s16x8 qf[2];
    #pragma unroll
    for (int ks = 0; ks < 2; ks++)
        qf[ks] = *(const s16x8*)(Qb + gQ + (size_t)(q0 + l15) * 64 + ks * 32 + lg * 8);

    float la[4] = {0.f, 0.f, 0.f, 0.f}, lc[4] = {0.f, 0.f, 0.f, 0.f};
    const int srow = lane >> 2, sjj = lane & 3;

    #pragma unroll 1
    for (int it = 0; it < 16; it++) {
        const int kb = it * 64;
        f32x4 sa[4] = {};
        s16x8 kf[8];
        #pragma unroll
        for (int ks = 0; ks < 2; ks++)
            #pragma unroll
            for (int n = 0; n < 4; n++)
                kf[ks * 4 + n] = *(const s16x8*)(Kb + gQ + (size_t)(kb + n * 16 + l15) * 64 + ks * 32 + lg * 8);
        #pragma unroll
        for (int ks = 0; ks < 2; ks++)
            #pragma unroll
            for (int n = 0; n < 4; n++)
                sa[n] = MFMA16(qf[ks], kf[ks * 4 + n], sa[n]);
        #pragma unroll
        for (int n = 0; n < 4; n++) {
            float fav = fa[g * 1024 + kb + n * 16 + l15];
            float fcv = fc[g * 1024 + kb + n * 16 + l15];
            #pragma unroll
            for (int r = 0; r < 4; r++) {
                float er = b2f(f2b(__expf(sa[n][r] * scale)));
                la[r] += er * fav;
                lc[r] += er * fcv;
                lE[w][lg * 4 + r][n * 16 + l15] = er;
            }
        }
        {
            const float* lp = &lE[w][srow][sjj * 16];
            uint4 p0, p1;
            p0.x = (u32)f2b(lp[0]) | ((u32)f2b(lp[1]) << 16);
            p0.y = (u32)f2b(lp[2]) | ((u32)f2b(lp[3]) << 16);
            p0.z = (u32)f2b(lp[4]) | ((u32)f2b(lp[5]) << 16);
            p0.w = (u32)f2b(lp[6]) | ((u32)f2b(lp[7]) << 16);
            p1.x = (u32)f2b(lp[8]) | ((u32)f2b(lp[9]) << 16);
            p1.y = (u32)f2b(lp[10]) | ((u32)f2b(lp[11]) << 16);
            p1.z = (u32)f2b(lp[12]) | ((u32)f2b(lp[13]) << 16);
            p1.w = (u32)f2b(lp[14]) | ((u32)f2b(lp[15]) << 16);
            u16* ep = E0 + (size_t)g * 1048576 + (size_t)(q0 + srow) * 1024 + kb + sjj * 16;
            *(uint4*)ep = p0;
            *(uint4*)(ep + 8) = p1;
        }
    }
    #pragma unroll
    for (int r = 0; r < 4; r++)
        #pragma unroll
        for (int m = 8; m >= 1; m >>= 1) {
            la[r] += __shfl_xor(la[r], m);
            lc[r] += __shfl_xor(lc[r], m);
        }
    if (l15 == 0) {
        #pragma unroll
        for (int r = 0; r < 4; r++) {
            la_[g * 1024 + q0 + lg * 4 + r] = la[r];
            lc_[g * 1024 + q0 + lg * 4 + r] = lc[r];
        }
    }
}

// ---------------- barrier-free fused mask-PV: zero LDS, zero syncthreads ----------------
// Lane computes P directly in MFMA A-frag layout (row=l15, cols lg*8+ks*32): no LDS
// transpose needed. Pure k_pmul-class streaming (occupancy is the latency hider) with
// MFMA consuming P in-register. V/fa/fc L2-hot; masks+E0 stream from HBM.
__global__ __launch_bounds__(256) void k_pv3(const u16* __restrict__ E0, const u16* __restrict__ Vt,
                                             const float* __restrict__ Ma_g, const float* __restrict__ Mc_g,
                                             const float* __restrict__ fa, const float* __restrict__ fc,
                                             const float* __restrict__ la, const float* __restrict__ lc,
                                             u16* __restrict__ ctx) {
    const int bid = blockIdx.x;
    const int xcd = bid & 7, j = bid >> 3;
    const int g = xcd * 8 + (j & 7), qt = j >> 3;
    const int tid = threadIdx.x, lane = tid & 63, w = tid >> 6;
    const int l15 = lane & 15, lg = lane >> 4;
    const int q0 = qt * 64;
    const int row = q0 + w * 16 + l15;  // this lane's P row (A-frag layout)
    const size_t gE = (size_t)g * 1048576;
    const size_t gV = (size_t)g * 65536;

    const float* __restrict__ mrowA = Ma_g + gE + (size_t)row * 1024;
    const float* __restrict__ mrowC = Mc_g + gE + (size_t)row * 1024;
    const u16* __restrict__ erow = E0 + gE + (size_t)row * 1024;
    const float* __restrict__ fag = fa + g * 1024;
    const float* __restrict__ fcg = fc + g * 1024;
    const float ila = 1.f / la[g * 1024 + row];
    const float ilc = 1.f / lc[g * 1024 + row];

    f32x4 ca[4] = {};

    #pragma unroll 1
    for (int it = 0; it < 16; it++) {
        const int kb = it * 64;
        #pragma unroll
        for (int ks = 0; ks < 2; ks++) {
            const int kc = kb + ks * 32 + lg * 8;
            float4 m0 = *(const float4*)(mrowA + kc);
            float4 m1 = *(const float4*)(mrowA + kc + 4);
            float4 n0 = *(const float4*)(mrowC + kc);
            float4 n1 = *(const float4*)(mrowC + kc + 4);
            s16x8 e = *(const s16x8*)(erow + kc);
            float4 a0 = *(const float4*)(fag + kc);
            float4 a1 = *(const float4*)(fag + kc + 4);
            float4 c0 = *(const float4*)(fcg + kc);
            float4 c1 = *(const float4*)(fcg + kc + 4);
            union { s16x8 v; u16 u[8]; } pf;
            pf.u[0] = f2b(b2f((u16)e[0]) * (a0.x * m0.x * ila + c0.x * n0.x * ilc));
            pf.u[1] = f2b(b2f((u16)e[1]) * (a0.y * m0.y * ila + c0.y * n0.y * ilc));
            pf.u[2] = f2b(b2f((u16)e[2]) * (a0.z * m0.z * ila + c0.z * n0.z * ilc));
            pf.u[3] = f2b(b2f((u16)e[3]) * (a0.w * m0.w * ila + c0.w * n0.w * ilc));
            pf.u[4] = f2b(b2f((u16)e[4]) * (a1.x * m1.x * ila + c1.x * n1.x * ilc));
            pf.u[5] = f2b(b2f((u16)e[5]) * (a1.y * m1.y * ila + c1.y * n1.y * ilc));
            pf.u[6] = f2b(b2f((u16)e[6]) * (a1.z * m1.z * ila + c1.z * n1.z * ilc));
            pf.u[7] = f2b(b2f((u16)e[7]) * (a1.w * m1.w * ila + c1.w * n1.w * ilc));
            #pragma unroll
            for (int d = 0; d < 4; d++) {
                s16x8 vf = *(const s16x8*)(Vt + gV + (size_t)(d * 16 + l15) * 1024 + kc);
                ca[d] = MFMA16(pf.v, vf, ca[d]);
            }
        }
    }
    #pragma unroll
    for (int n = 0; n < 4; n++) {
        int col = n * 16 + l15;
        int row0 = q0 + w * 16 + lg * 4;
        #pragma unroll
        for (int r = 0; r < 4; r++)
            ctx[gV + (size_t)(row0 + r) * 64 + col] = f2b(ca[n][r]);
    }
}

// ---------------- row LayerNorm ----------------
__global__ __launch_bounds__(256) void k_ln(const float* __restrict__ a, const float* __restrict__ bias,
                                            const float* __restrict__ resid, const float* __restrict__ gamma,
                                            const float* __restrict__ beta, float* __restrict__ out,
                                            u16* __restrict__ outb) {
    const int row = blockIdx.x, tid = threadIdx.x;
    const size_t base = (size_t)row * 1024 + tid * 4;
    float4 av = *(const float4*)(a + base);
    float4 rv = *(const float4*)(resid + base);
    float4 bv = *(const float4*)(bias + tid * 4);
    float t0 = av.x + rv.x + bv.x, t1 = av.y + rv.y + bv.y;
    float t2 = av.z + rv.z + bv.z, t3 = av.w + rv.w + bv.w;
    __shared__ float red[4];
    float s = t0 + t1 + t2 + t3;
    #pragma unroll
    for (int m = 32; m >= 1; m >>= 1) s += __shfl_xor(s, m);
    int w = tid >> 6;
    if ((tid & 63) == 0) red[w] = s;
    __syncthreads();
    float mean = (red[0] + red[1] + red[2] + red[3]) * (1.f / 1024.f);
    float d0 = t0 - mean, d1 = t1 - mean, d2 = t2 - mean, d3 = t3 - mean;
    float q = d0 * d0 + d1 * d1 + d2 * d2 + d3 * d3;
    __syncthreads();
    #pragma unroll
    for (int m = 32; m >= 1; m >>= 1) q += __shfl_xor(q, m);
    if ((tid & 63) == 0) red[w] = q;
    __syncthreads();
    float var = (red[0] + red[1] + red[2] + red[3]) * (1.f / 1024.f);
    float rs = rsqrtf(var + 1e-5f);
    float4 gv = *(const float4*)(gamma + tid * 4);
    float4 bev = *(const float4*)(beta + tid * 4);
    float o0 = d0 * rs * gv.x + bev.x, o1 = d1 * rs * gv.y + bev.y;
    float o2 = d2 * rs * gv.z + bev.z, o3 = d3 * rs * gv.w + bev.w;
    *(float4*)(out + base) = make_float4(o0, o1, o2, o3);
    if (outb) {
        ushort4 ob;
        ob.x = f2b(o0); ob.y = f2b(o1); ob.z = f2b(o2); ob.w = f2b(o3);
        *(ushort4*)(outb + base) = ob;
    }
}

extern "C" void kernel_launch(void* const* d_in, const int* in_sizes, int n_in,
                              void* d_out, int out_size, void* d_ws, size_t ws_size,
                              hipStream_t stream) {
    const float* x    = (const float*)d_in[0];
    const float* adjm = (const float*)d_in[1];
    const float* comm = (const float*)d_in[2];
    const float* rel  = (const float*)d_in[3];
    const float* Wq   = (const float*)d_in[4];
    const float* bq   = (const float*)d_in[5];
    const float* Wk   = (const float*)d_in[6];
    const float* bk   = (const float*)d_in[7];
    const float* Wv   = (const float*)d_in[8];
    const float* bv   = (const float*)d_in[9];
    const float* Wo   = (const float*)d_in[10];
    const float* bo   = (const float*)d_in[11];
    const float* g1   = (const float*)d_in[12];
    const float* be1  = (const float*)d_in[13];
    const float* W1   = (const float*)d_in[14];
    const float* b1   = (const float*)d_in[15];
    const float* W2   = (const float*)d_in[16];
    const float* b2   = (const float*)d_in[17];
    const float* g2   = (const float*)d_in[18];
    const float* be2  = (const float*)d_in[19];
    float* out = (float*)d_out;

    char* ws = (char*)d_ws;
    const size_t MB = 1048576;
    u16*   xb    = (u16*)(ws + 0 * MB);      // 8 MiB (dead after gemm_qkv)
    u16*   Wqkvt = (u16*)(ws + 8 * MB);      // 6 MiB
    u16*   Wot   = (u16*)(ws + 14 * MB);     // 2 MiB
    u16*   W1t   = (u16*)(ws + 16 * MB);     // 8 MiB
    u16*   W2t   = (u16*)(ws + 24 * MB);     // 8 MiB (live through FFN2)
    u16*   Qb    = (u16*)(ws + 32 * MB);     // 8 MiB
    u16*   Kb    = (u16*)(ws + 40 * MB);     // 8 MiB
    u16*   Vtb   = (u16*)(ws + 48 * MB);     // 8 MiB
    float* faB   = (float*)(ws + 56 * MB);   // 256 KiB each: fa, fc, la, lc
    float* fcB   = (float*)(ws + 56 * MB + 262144);
    float* laB   = (float*)(ws + 56 * MB + 524288);
    float* lcB   = (float*)(ws + 56 * MB + 786432);
    u16*   E0b   = (u16*)(ws + 57 * MB);     // 128 MiB [57,185)
    u16*   ctx   = (u16*)(ws + 185 * MB);    // 8 MiB
    float* ctxWo = (float*)(ws + 193 * MB);  // 16 MiB
    float* out1  = (float*)(ws + 209 * MB);  // 16 MiB (live to LN2)
    u16*   out1b = (u16*)(ws + 225 * MB);    // 8 MiB
    u16*   rb    = (u16*)(ws + 233 * MB);    // 32 MiB (FFN1 out)
    float* ff2   = (float*)(ws + 265 * MB);  // 16 MiB

    dim3 tb(32, 8);
    // 1. casts / weight prep
    k_f2b<<<4096, 256, 0, stream>>>(x, xb, 1048576);
    k_wtrans<<<dim3(32, 32), tb, 0, stream>>>(Wq, Wqkvt, 1024, 1024);
    k_wtrans<<<dim3(32, 32), tb, 0, stream>>>(Wk, Wqkvt + 1024 * 1024, 1024, 1024);
    k_wtrans<<<dim3(32, 32), tb, 0, stream>>>(Wv, Wqkvt + 2 * 1024 * 1024, 1024, 1024);
    k_wtrans<<<dim3(32, 32), tb, 0, stream>>>(Wo, Wot, 1024, 1024);
    k_wtrans<<<dim3(128, 32), tb, 0, stream>>>(W1, W1t, 1024, 4096);
    k_wtrans<<<dim3(32, 128), tb, 0, stream>>>(W2, W2t, 4096, 1024);
    // 2. fused QKV projection (plain Q,K + transposed V)
    gemm_qkv<<<dim3(24, 32), 256, 0, stream>>>(xb, Wqkvt, bq, bk, bv, Qb, Kb, Vtb);
    // 3. attention via softmax factorization + barrier-free fused mask-PV
    k_fvec<<<64, 256, 0, stream>>>(Kb, rel, faB, fcB);
    k_qke0<<<1024, 256, 0, stream>>>(Qb, Kb, faB, fcB, E0b, laB, lcB);
    k_pv3<<<1024, 256, 0, stream>>>(E0b, Vtb, adjm, comm, faB, fcB, laB, lcB, ctx);
    // 4. output projection + LN1
    gemm_bt64<<<dim3(16, 32), 256, 0, stream>>>(ctx, Wot, ctxWo, 4096, 1024, 1024);
    k_ln<<<4096, 256, 0, stream>>>(ctxWo, bo, x, g1, be1, out1, out1b);
    // 5. FFN
    gemm_bt<1><<<dim3(32, 32), 256, 0, stream>>>(out1b, W1t, rb, 4096, 4096, 1024, b1);
    gemm_bt64<<<dim3(16, 32), 256, 0, stream>>>(rb, W2t, ff2, 4096, 1024, 4096);
    // 6. LN2 -> final output
    k_ln<<<4096, 256, 0, stream>>>(ff2, b2, out1, g2, be2, out, nullptr);
}

// Round 16
// 534.425 us; speedup vs baseline: 1.0763x; 1.0763x over previous
//
#include <hip/hip_runtime.h>
#include <hip/hip_bf16.h>

typedef __attribute__((ext_vector_type(8))) short s16x8;
typedef __attribute__((ext_vector_type(4))) float f32x4;
typedef unsigned short u16;
typedef unsigned int u32;

__device__ __forceinline__ u16 f2b(float f) {
    u32 u = __float_as_uint(f);
    u32 r = (u + 0x7fffu + ((u >> 16) & 1u)) >> 16;  // RNE bf16
    return (u16)r;
}
__device__ __forceinline__ float b2f(u16 b) {
    return __uint_as_float(((u32)b) << 16);
}

#define MFMA16(a, b, c) __builtin_amdgcn_mfma_f32_16x16x32_bf16(a, b, c, 0, 0, 0)
#define GLDS(gp, lp)                                                              \
    __builtin_amdgcn_global_load_lds((const __attribute__((address_space(1))) void*)(gp), \
                                     (__attribute__((address_space(3))) void*)(lp), 16, 0, 0)

// ---------------- elementwise: f32 -> bf16 ----------------
__global__ void k_f2b(const float* __restrict__ in, u16* __restrict__ out, int n4) {
    int i = blockIdx.x * 256 + threadIdx.x;
    if (i >= n4) return;
    float4 v = ((const float4*)in)[i];
    ushort4 o;
    o.x = f2b(v.x); o.y = f2b(v.y); o.z = f2b(v.z); o.w = f2b(v.w);
    ((ushort4*)out)[i] = o;
}

// ---------------- weight transpose+convert: W[K,N] f32 -> Wt[N,K] bf16 ----------------
__global__ void k_wtrans(const float* __restrict__ W, u16* __restrict__ Wt, int K, int N) {
    __shared__ float t[32][33];
    int bx = blockIdx.x * 32, by = blockIdx.y * 32;
    int tx = threadIdx.x, ty = threadIdx.y;
    for (int i = 0; i < 32; i += 8)
        t[ty + i][tx] = W[(size_t)(by + ty + i) * N + bx + tx];
    __syncthreads();
    for (int i = 0; i < 32; i += 8)
        Wt[(size_t)(bx + ty + i) * K + by + tx] = f2b(t[tx][ty + i]);
}

// ---------------- fused QKV GEMM: epilogue writes Qb/Kb (bias only) + transposed Vt ----------------
__global__ __launch_bounds__(256) void gemm_qkv(const u16* __restrict__ A, const u16* __restrict__ Bt,
                                                const float* __restrict__ bq, const float* __restrict__ bk,
                                                const float* __restrict__ bv,
                                                u16* __restrict__ Qb, u16* __restrict__ Kb,
                                                u16* __restrict__ Vt) {
    __shared__ __align__(16) short lA[128 * 64];
    __shared__ __align__(16) short lB[128 * 64];
    const int tid = threadIdx.x, lane = tid & 63, w = tid >> 6;
    const int l15 = lane & 15, lg = lane >> 4;
    const int wr = w >> 1, wc = w & 1;
    const int m0 = blockIdx.y * 128, n0 = blockIdx.x * 128;
    const int KK = 1024;
    f32x4 acc[4][4] = {};

    for (int k0 = 0; k0 < KK; k0 += 64) {
        #pragma unroll
        for (int i = 0; i < 4; i++) {
            int chunk = w * 4 + i;
            int arow = m0 + chunk * 8 + (lane >> 3);
            GLDS(A + (size_t)arow * KK + k0 + (lane & 7) * 8, (short*)lA + chunk * 512);
            int brow = n0 + chunk * 8 + (lane >> 3);
            GLDS(Bt + (size_t)brow * KK + k0 + (lane & 7) * 8, (short*)lB + chunk * 512);
        }
        __syncthreads();
        #pragma unroll
        for (int ks = 0; ks < 2; ks++) {
            s16x8 af[4], bfr[4];
            #pragma unroll
            for (int m = 0; m < 4; m++)
                af[m] = *(const s16x8*)&lA[(wr * 64 + m * 16 + l15) * 64 + ks * 32 + lg * 8];
            #pragma unroll
            for (int n = 0; n < 4; n++)
                bfr[n] = *(const s16x8*)&lB[(wc * 64 + n * 16 + l15) * 64 + ks * 32 + lg * 8];
            #pragma unroll
            for (int m = 0; m < 4; m++)
                #pragma unroll
                for (int n = 0; n < 4; n++)
                    acc[m][n] = MFMA16(af[m], bfr[n], acc[m][n]);
        }
        __syncthreads();
    }
    const int rbase = m0 + wr * 64, cbase = n0 + wc * 64;
    const int seg = cbase >> 10;
    #pragma unroll
    for (int m = 0; m < 4; m++)
        #pragma unroll
        for (int n = 0; n < 4; n++) {
            int col = cbase + n * 16 + l15;
            int c1 = col & 1023, d = col & 63;
            int row0 = rbase + m * 16 + lg * 4;
            if (seg == 0) {
                float bb = bq[c1];
                #pragma unroll
                for (int r = 0; r < 4; r++)
                    Qb[(size_t)(row0 + r) * 1024 + c1] = f2b(acc[m][n][r] + bb);
            } else if (seg == 1) {
                float bb = bk[c1];
                #pragma unroll
                for (int r = 0; r < 4; r++)
                    Kb[(size_t)(row0 + r) * 1024 + c1] = f2b(acc[m][n][r] + bb);
            } else {
                float bb = bv[c1];
                #pragma unroll
                for (int r = 0; r < 4; r++) {
                    int row = row0 + r;
                    size_t o = (size_t)(row >> 6) * 65536 + (size_t)d * 1024 + (row & 63) * 16 + (c1 >> 6);
                    Vt[o] = f2b(acc[m][n][r] + bb);
                }
            }
        }
}

// ---------------- GEMM 128x128, EPI 1: bf16(relu(acc+bias)) ----------------
template <int EPI>
__global__ __launch_bounds__(256) void gemm_bt(const u16* __restrict__ A, const u16* __restrict__ Bt,
                                               void* __restrict__ Cv, int M, int N, int K,
                                               const float* __restrict__ bias) {
    __shared__ __align__(16) short lA[128 * 64];
    __shared__ __align__(16) short lB[128 * 64];
    const int tid = threadIdx.x, lane = tid & 63, w = tid >> 6;
    const int l15 = lane & 15, lg = lane >> 4;
    const int wr = w >> 1, wc = w & 1;
    const int m0 = blockIdx.y * 128, n0 = blockIdx.x * 128;
    f32x4 acc[4][4] = {};

    for (int k0 = 0; k0 < K; k0 += 64) {
        #pragma unroll
        for (int i = 0; i < 4; i++) {
            int chunk = w * 4 + i;
            int arow = m0 + chunk * 8 + (lane >> 3);
            GLDS(A + (size_t)arow * K + k0 + (lane & 7) * 8, (short*)lA + chunk * 512);
            int brow = n0 + chunk * 8 + (lane >> 3);
            GLDS(Bt + (size_t)brow * K + k0 + (lane & 7) * 8, (short*)lB + chunk * 512);
        }
        __syncthreads();
        #pragma unroll
        for (int ks = 0; ks < 2; ks++) {
            s16x8 af[4], bfr[4];
            #pragma unroll
            for (int m = 0; m < 4; m++)
                af[m] = *(const s16x8*)&lA[(wr * 64 + m * 16 + l15) * 64 + ks * 32 + lg * 8];
            #pragma unroll
            for (int n = 0; n < 4; n++)
                bfr[n] = *(const s16x8*)&lB[(wc * 64 + n * 16 + l15) * 64 + ks * 32 + lg * 8];
            #pragma unroll
            for (int m = 0; m < 4; m++)
                #pragma unroll
                for (int n = 0; n < 4; n++)
                    acc[m][n] = MFMA16(af[m], bfr[n], acc[m][n]);
        }
        __syncthreads();
    }
    const int rbase = m0 + wr * 64, cbase = n0 + wc * 64;
    #pragma unroll
    for (int m = 0; m < 4; m++)
        #pragma unroll
        for (int n = 0; n < 4; n++) {
            int col = cbase + n * 16 + l15;
            int row0 = rbase + m * 16 + lg * 4;
            u16* C = (u16*)Cv;
            float bv = bias[col];
            #pragma unroll
            for (int r = 0; r < 4; r++)
                C[(size_t)(row0 + r) * N + col] = f2b(fmaxf(acc[m][n][r] + bv, 0.f));
        }
}

// ---------------- GEMM 128x64 f32-out ----------------
__global__ __launch_bounds__(256) void gemm_bt64(const u16* __restrict__ A, const u16* __restrict__ Bt,
                                                 float* __restrict__ C, int M, int N, int K) {
    __shared__ __align__(16) short lA[128 * 64];
    __shared__ __align__(16) short lB[64 * 64];
    const int tid = threadIdx.x, lane = tid & 63, w = tid >> 6;
    const int l15 = lane & 15, lg = lane >> 4;
    const int m0 = blockIdx.y * 128, n0 = blockIdx.x * 64;
    f32x4 acc[2][4] = {};

    for (int k0 = 0; k0 < K; k0 += 64) {
        #pragma unroll
        for (int i = 0; i < 4; i++) {
            int chunk = w * 4 + i;
            int arow = m0 + chunk * 8 + (lane >> 3);
            GLDS(A + (size_t)arow * K + k0 + (lane & 7) * 8, (short*)lA + chunk * 512);
        }
        #pragma unroll
        for (int i = 0; i < 2; i++) {
            int chunk = w * 2 + i;
            int brow = n0 + chunk * 8 + (lane >> 3);
            GLDS(Bt + (size_t)brow * K + k0 + (lane & 7) * 8, (short*)lB + chunk * 512);
        }
        __syncthreads();
        #pragma unroll
        for (int ks = 0; ks < 2; ks++) {
            s16x8 af[2], bfr[4];
            #pragma unroll
            for (int m = 0; m < 2; m++)
                af[m] = *(const s16x8*)&lA[(w * 32 + m * 16 + l15) * 64 + ks * 32 + lg * 8];
            #pragma unroll
            for (int n = 0; n < 4; n++)
                bfr[n] = *(const s16x8*)&lB[(n * 16 + l15) * 64 + ks * 32 + lg * 8];
            #pragma unroll
            for (int m = 0; m < 2; m++)
                #pragma unroll
                for (int n = 0; n < 4; n++)
                    acc[m][n] = MFMA16(af[m], bfr[n], acc[m][n]);
        }
        __syncthreads();
    }
    #pragma unroll
    for (int m = 0; m < 2; m++)
        #pragma unroll
        for (int n = 0; n < 4; n++) {
            int col = n0 + n * 16 + l15;
            int row0 = m0 + w * 32 + m * 16 + lg * 4;
            #pragma unroll
            for (int r = 0; r < 4; r++)
                C[(size_t)(row0 + r) * N + col] = acc[m][n][r];
        }
}

// ---------------- fa/fc: per-k rel factors fa[g,k]=exp(ra.K[g,k]/8) ----------------
__global__ void k_fvec(const u16* __restrict__ Kb, const float* __restrict__ rel,
                       float* __restrict__ fa, float* __restrict__ fc) {
    __shared__ float rs[128];
    const int g = blockIdx.x, tid = threadIdx.x;
    if (tid < 128) rs[tid] = rel[tid];
    __syncthreads();
    for (int k = tid; k < 1024; k += 256) {
        const u16* kr = Kb + (size_t)g * 65536 + (size_t)k * 64;
        float sa = 0.f, sc = 0.f;
        #pragma unroll
        for (int j = 0; j < 8; j++) {
            s16x8 v = *(const s16x8*)(kr + j * 8);
            #pragma unroll
            for (int e = 0; e < 8; e++) {
                float kv = b2f((u16)v[e]);
                sa += kv * rs[j * 8 + e];
                sc += kv * rs[64 + j * 8 + e];
            }
        }
        fa[g * 1024 + k] = __expf(sa * 0.125f);
        fc[g * 1024 + k] = __expf(sc * 0.125f);
    }
}

// ---------------- E0 = exp(QK^T/8) bf16 row-major + denominators la,lc ----------------
__global__ __launch_bounds__(256, 2) void k_qke0(const u16* __restrict__ Qb, const u16* __restrict__ Kb,
                                                 const float* __restrict__ fa, const float* __restrict__ fc,
                                                 u16* __restrict__ E0,
                                                 float* __restrict__ la_, float* __restrict__ lc_) {
    const int bid = blockIdx.x;
    const int xcd = bid & 7, j = bid >> 3;
    const int g = xcd * 8 + (j & 7), qt = j >> 3;
    const int tid = threadIdx.x, lane = tid & 63, w = tid >> 6;
    const int l15 = lane & 15, lg = lane >> 4;
    __shared__ __align__(16) float lE[4][16][68];

    const int q0 = qt * 64 + w * 16;
    const size_t gQ = (size_t)g * 65536;
    const float scale = 0.125f;

    s16x8 qf[2];
    #pragma unroll
    for (int ks = 0; ks < 2; ks++)
        qf[ks] = *(const s16x8*)(Qb + gQ + (size_t)(q0 + l15) * 64 + ks * 32 + lg * 8);

    float la[4] = {0.f, 0.f, 0.f, 0.f}, lc[4] = {0.f, 0.f, 0.f, 0.f};
    const int srow = lane >> 2, sjj = lane & 3;

    #pragma unroll 1
    for (int it = 0; it < 16; it++) {
        const int kb = it * 64;
        f32x4 sa[4] = {};
        s16x8 kf[8];
        #pragma unroll
        for (int ks = 0; ks < 2; ks++)
            #pragma unroll
            for (int n = 0; n < 4; n++)
                kf[ks * 4 + n] = *(const s16x8*)(Kb + gQ + (size_t)(kb + n * 16 + l15) * 64 + ks * 32 + lg * 8);
        #pragma unroll
        for (int ks = 0; ks < 2; ks++)
            #pragma unroll
            for (int n = 0; n < 4; n++)
                sa[n] = MFMA16(qf[ks], kf[ks * 4 + n], sa[n]);
        #pragma unroll
        for (int n = 0; n < 4; n++) {
            float fav = fa[g * 1024 + kb + n * 16 + l15];
            float fcv = fc[g * 1024 + kb + n * 16 + l15];
            #pragma unroll
            for (int r = 0; r < 4; r++) {
                float er = b2f(f2b(__expf(sa[n][r] * scale)));
                la[r] += er * fav;
                lc[r] += er * fcv;
                lE[w][lg * 4 + r][n * 16 + l15] = er;
            }
        }
        {
            const float* lp = &lE[w][srow][sjj * 16];
            uint4 p0, p1;
            p0.x = (u32)f2b(lp[0]) | ((u32)f2b(lp[1]) << 16);
            p0.y = (u32)f2b(lp[2]) | ((u32)f2b(lp[3]) << 16);
            p0.z = (u32)f2b(lp[4]) | ((u32)f2b(lp[5]) << 16);
            p0.w = (u32)f2b(lp[6]) | ((u32)f2b(lp[7]) << 16);
            p1.x = (u32)f2b(lp[8]) | ((u32)f2b(lp[9]) << 16);
            p1.y = (u32)f2b(lp[10]) | ((u32)f2b(lp[11]) << 16);
            p1.z = (u32)f2b(lp[12]) | ((u32)f2b(lp[13]) << 16);
            p1.w = (u32)f2b(lp[14]) | ((u32)f2b(lp[15]) << 16);
            u16* ep = E0 + (size_t)g * 1048576 + (size_t)(q0 + srow) * 1024 + kb + sjj * 16;
            *(uint4*)ep = p0;
            *(uint4*)(ep + 8) = p1;
        }
    }
    #pragma unroll
    for (int r = 0; r < 4; r++)
        #pragma unroll
        for (int m = 8; m >= 1; m >>= 1) {
            la[r] += __shfl_xor(la[r], m);
            lc[r] += __shfl_xor(lc[r], m);
        }
    if (l15 == 0) {
        #pragma unroll
        for (int r = 0; r < 4; r++) {
            la_[g * 1024 + q0 + lg * 4 + r] = la[r];
            lc_[g * 1024 + q0 + lg * 4 + r] = lc[r];
        }
    }
}

// ---------------- fused P-compute + PV GEMM ----------------
// Best-measured attention tail (R13, total 561.99 us). Masks staged via GLDS (no VGPR
// dest -> full-tile MLP); P computed in LDS, fed to MFMA.
__global__ __launch_bounds__(256) void gemm_pvf(const u16* __restrict__ E0, const u16* __restrict__ Vt,
                                                const float* __restrict__ Ma_g, const float* __restrict__ Mc_g,
                                                const float* __restrict__ fa, const float* __restrict__ fc,
                                                const float* __restrict__ la, const float* __restrict__ lc,
                                                u16* __restrict__ ctx) {
    __shared__ __align__(16) float bufMa[64 * 64];   // 16 KB
    __shared__ __align__(16) float bufMc[64 * 64];   // 16 KB
    __shared__ __align__(16) short bufP[64 * 68];    // 8.5 KB (padded rows)
    __shared__ __align__(16) short bufV[64 * 68];    // 8.5 KB
    __shared__ __align__(16) float lfa[1024];        // 4 KB
    __shared__ __align__(16) float lfc[1024];        // 4 KB

    const int bid = blockIdx.x;
    const int xcd = bid & 7, j = bid >> 3;
    const int g = xcd * 8 + (j & 7), qt = j >> 3;
    const int tid = threadIdx.x, lane = tid & 63, w = tid >> 6;
    const int l15 = lane & 15, lg = lane >> 4;
    const int q0 = qt * 64;
    const size_t gE = (size_t)g * 1048576;
    const size_t gV = (size_t)g * 65536;

    GLDS(fa + g * 1024 + w * 256 + (lane & 63) * 4, lfa + w * 256);
    GLDS(fc + g * 1024 + w * 256 + (lane & 63) * 4, lfc + w * 256);
    const int pr = tid >> 2, pc = (tid & 3) * 16;
    const float ila = 1.f / la[g * 1024 + q0 + pr];
    const float ilc = 1.f / lc[g * 1024 + q0 + pr];
    const int vd = tid >> 2, vc = (tid & 3) * 16;

    f32x4 acc[4] = {};
    __syncthreads();

    #pragma unroll 1
    for (int it = 0; it < 16; it++) {
        const int kb = it * 64;
        #pragma unroll
        for (int o = 0; o < 4; o++) {
            int op = w * 4 + o;
            int row = op * 4 + (lane >> 4);
            int ch = lane & 15;
            GLDS(Ma_g + (size_t)g * 1048576 + (size_t)(q0 + row) * 1024 + kb + ch * 4, bufMa + op * 256);
            GLDS(Mc_g + (size_t)g * 1048576 + (size_t)(q0 + row) * 1024 + kb + ch * 4, bufMc + op * 256);
        }
        s16x8 v0 = *(const s16x8*)(Vt + gV + (size_t)vd * 1024 + kb + vc);
        s16x8 v1 = *(const s16x8*)(Vt + gV + (size_t)vd * 1024 + kb + vc + 8);
        s16x8 e0 = *(const s16x8*)(E0 + gE + (size_t)(q0 + pr) * 1024 + kb + pc);
        s16x8 e1 = *(const s16x8*)(E0 + gE + (size_t)(q0 + pr) * 1024 + kb + pc + 8);
        *(s16x8*)&bufV[vd * 68 + vc] = v0;
        *(s16x8*)&bufV[vd * 68 + vc + 8] = v1;
        __syncthreads();
        {
            const float* map = &bufMa[pr * 64 + pc];
            const float* mcp = &bufMc[pr * 64 + pc];
            const float* fap = &lfa[kb + pc];
            const float* fcp = &lfc[kb + pc];
            union { s16x8 v; u16 u[8]; } o0, o1;
            #pragma unroll
            for (int e = 0; e < 8; e++) {
                float t = fap[e] * map[e] * ila + fcp[e] * mcp[e] * ilc;
                o0.u[e] = f2b(b2f((u16)e0[e]) * t);
            }
            #pragma unroll
            for (int e = 0; e < 8; e++) {
                float t = fap[8 + e] * map[8 + e] * ila + fcp[8 + e] * mcp[8 + e] * ilc;
                o1.u[e] = f2b(b2f((u16)e1[e]) * t);
            }
            *(s16x8*)&bufP[pr * 68 + pc] = o0.v;
            *(s16x8*)&bufP[pr * 68 + pc + 8] = o1.v;
        }
        __syncthreads();
        #pragma unroll
        for (int ks = 0; ks < 2; ks++) {
            s16x8 af = *(const s16x8*)&bufP[(w * 16 + l15) * 68 + ks * 32 + lg * 8];
            #pragma unroll
            for (int n = 0; n < 4; n++) {
                s16x8 bfr = *(const s16x8*)&bufV[(n * 16 + l15) * 68 + ks * 32 + lg * 8];
                acc[n] = MFMA16(af, bfr, acc[n]);
            }
        }
        __syncthreads();
    }
    #pragma unroll
    for (int n = 0; n < 4; n++) {
        int col = n * 16 + l15;
        int row0 = q0 + w * 16 + lg * 4;
        #pragma unroll
        for (int r = 0; r < 4; r++)
            ctx[gV + (size_t)(row0 + r) * 64 + col] = f2b(acc[n][r]);
    }
}

// ---------------- row LayerNorm ----------------
__global__ __launch_bounds__(256) void k_ln(const float* __restrict__ a, const float* __restrict__ bias,
                                            const float* __restrict__ resid, const float* __restrict__ gamma,
                                            const float* __restrict__ beta, float* __restrict__ out,
                                            u16* __restrict__ outb) {
    const int row = blockIdx.x, tid = threadIdx.x;
    const size_t base = (size_t)row * 1024 + tid * 4;
    float4 av = *(const float4*)(a + base);
    float4 rv = *(const float4*)(resid + base);
    float4 bv = *(const float4*)(bias + tid * 4);
    float t0 = av.x + rv.x + bv.x, t1 = av.y + rv.y + bv.y;
    float t2 = av.z + rv.z + bv.z, t3 = av.w + rv.w + bv.w;
    __shared__ float red[4];
    float s = t0 + t1 + t2 + t3;
    #pragma unroll
    for (int m = 32; m >= 1; m >>= 1) s += __shfl_xor(s, m);
    int w = tid >> 6;
    if ((tid & 63) == 0) red[w] = s;
    __syncthreads();
    float mean = (red[0] + red[1] + red[2] + red[3]) * (1.f / 1024.f);
    float d0 = t0 - mean, d1 = t1 - mean, d2 = t2 - mean, d3 = t3 - mean;
    float q = d0 * d0 + d1 * d1 + d2 * d2 + d3 * d3;
    __syncthreads();
    #pragma unroll
    for (int m = 32; m >= 1; m >>= 1) q += __shfl_xor(q, m);
    if ((tid & 63) == 0) red[w] = q;
    __syncthreads();
    float var = (red[0] + red[1] + red[2] + red[3]) * (1.f / 1024.f);
    float rs = rsqrtf(var + 1e-5f);
    float4 gv = *(const float4*)(gamma + tid * 4);
    float4 bev = *(const float4*)(beta + tid * 4);
    float o0 = d0 * rs * gv.x + bev.x, o1 = d1 * rs * gv.y + bev.y;
    float o2 = d2 * rs * gv.z + bev.z, o3 = d3 * rs * gv.w + bev.w;
    *(float4*)(out + base) = make_float4(o0, o1, o2, o3);
    if (outb) {
        ushort4 ob;
        ob.x = f2b(o0); ob.y = f2b(o1); ob.z = f2b(o2); ob.w = f2b(o3);
        *(ushort4*)(outb + base) = ob;
    }
}

extern "C" void kernel_launch(void* const* d_in, const int* in_sizes, int n_in,
                              void* d_out, int out_size, void* d_ws, size_t ws_size,
                              hipStream_t stream) {
    const float* x    = (const float*)d_in[0];
    const float* adjm = (const float*)d_in[1];
    const float* comm = (const float*)d_in[2];
    const float* rel  = (const float*)d_in[3];
    const float* Wq   = (const float*)d_in[4];
    const float* bq   = (const float*)d_in[5];
    const float* Wk   = (const float*)d_in[6];
    const float* bk   = (const float*)d_in[7];
    const float* Wv   = (const float*)d_in[8];
    const float* bv   = (const float*)d_in[9];
    const float* Wo   = (const float*)d_in[10];
    const float* bo   = (const float*)d_in[11];
    const float* g1   = (const float*)d_in[12];
    const float* be1  = (const float*)d_in[13];
    const float* W1   = (const float*)d_in[14];
    const float* b1   = (const float*)d_in[15];
    const float* W2   = (const float*)d_in[16];
    const float* b2   = (const float*)d_in[17];
    const float* g2   = (const float*)d_in[18];
    const float* be2  = (const float*)d_in[19];
    float* out = (float*)d_out;

    char* ws = (char*)d_ws;
    const size_t MB = 1048576;
    u16*   xb    = (u16*)(ws + 0 * MB);      // 8 MiB (dead after gemm_qkv)
    u16*   Wqkvt = (u16*)(ws + 8 * MB);      // 6 MiB
    u16*   Wot   = (u16*)(ws + 14 * MB);     // 2 MiB
    u16*   W1t   = (u16*)(ws + 16 * MB);     // 8 MiB
    u16*   W2t   = (u16*)(ws + 24 * MB);     // 8 MiB (live through FFN2)
    u16*   Qb    = (u16*)(ws + 32 * MB);     // 8 MiB
    u16*   Kb    = (u16*)(ws + 40 * MB);     // 8 MiB
    u16*   Vtb   = (u16*)(ws + 48 * MB);     // 8 MiB
    float* faB   = (float*)(ws + 56 * MB);   // 256 KiB each: fa, fc, la, lc
    float* fcB   = (float*)(ws + 56 * MB + 262144);
    float* laB   = (float*)(ws + 56 * MB + 524288);
    float* lcB   = (float*)(ws + 56 * MB + 786432);
    u16*   E0b   = (u16*)(ws + 57 * MB);     // 128 MiB [57,185)
    u16*   ctx   = (u16*)(ws + 185 * MB);    // 8 MiB
    float* ctxWo = (float*)(ws + 193 * MB);  // 16 MiB
    float* out1  = (float*)(ws + 209 * MB);  // 16 MiB (live to LN2)
    u16*   out1b = (u16*)(ws + 225 * MB);    // 8 MiB
    u16*   rb    = (u16*)(ws + 233 * MB);    // 32 MiB (FFN1 out)
    float* ff2   = (float*)(ws + 265 * MB);  // 16 MiB

    dim3 tb(32, 8);
    // 1. casts / weight prep
    k_f2b<<<4096, 256, 0, stream>>>(x, xb, 1048576);
    k_wtrans<<<dim3(32, 32), tb, 0, stream>>>(Wq, Wqkvt, 1024, 1024);
    k_wtrans<<<dim3(32, 32), tb, 0, stream>>>(Wk, Wqkvt + 1024 * 1024, 1024, 1024);
    k_wtrans<<<dim3(32, 32), tb, 0, stream>>>(Wv, Wqkvt + 2 * 1024 * 1024, 1024, 1024);
    k_wtrans<<<dim3(32, 32), tb, 0, stream>>>(Wo, Wot, 1024, 1024);
    k_wtrans<<<dim3(128, 32), tb, 0, stream>>>(W1, W1t, 1024, 4096);
    k_wtrans<<<dim3(32, 128), tb, 0, stream>>>(W2, W2t, 4096, 1024);
    // 2. fused QKV projection (plain Q,K + transposed V)
    gemm_qkv<<<dim3(24, 32), 256, 0, stream>>>(xb, Wqkvt, bq, bk, bv, Qb, Kb, Vtb);
    // 3. attention via softmax factorization + fused mask-PV
    k_fvec<<<64, 256, 0, stream>>>(Kb, rel, faB, fcB);
    k_qke0<<<1024, 256, 0, stream>>>(Qb, Kb, faB, fcB, E0b, laB, lcB);
    gemm_pvf<<<1024, 256, 0, stream>>>(E0b, Vtb, adjm, comm, faB, fcB, laB, lcB, ctx);
    // 4. output projection + LN1
    gemm_bt64<<<dim3(16, 32), 256, 0, stream>>>(ctx, Wot, ctxWo, 4096, 1024, 1024);
    k_ln<<<4096, 256, 0, stream>>>(ctxWo, bo, x, g1, be1, out1, out1b);
    // 5. FFN
    gemm_bt<1><<<dim3(32, 32), 256, 0, stream>>>(out1b, W1t, rb, 4096, 4096, 1024, b1);
    gemm_bt64<<<dim3(16, 32), 256, 0, stream>>>(rb, W2t, ff2, 4096, 1024, 4096);
    // 6. LN2 -> final output
    k_ln<<<4096, 256, 0, stream>>>(ff2, b2, out1, g2, be2, out, nullptr);
}